// Round 6
// baseline (318.001 us; speedup 1.0000x reference)
//
#include <hip/hip_runtime.h>
#include <hip/hip_bf16.h>

typedef __attribute__((ext_vector_type(8))) short bf16x8;
typedef __attribute__((ext_vector_type(4))) float f32x4;

#define NE 8192
#define MT 32
#define DD 256
#define NAPP 262144
#define NSLOT (NE*MT)
#define NSYM 50000
#define NSYMP 50048

// ws layout (bytes)
#define WS_WINNER 0
#define WS_WTSW   (1u<<20)
#define WS_WTLIN  (2u<<20)
#define WS_SYMGC  (3u<<20)   // NSYMP*512*2B = 51.2MB

static __device__ __forceinline__ unsigned short f2b(float x){
  union{float f; unsigned u;} v; v.f = x;
  unsigned r = (v.u + 0x7fffu + ((v.u>>16)&1u))>>16;
  return (unsigned short)r;
}
static __device__ __forceinline__ unsigned pk2(float a, float b){
  return (unsigned)f2b(a) | ((unsigned)f2b(b)<<16);
}
static __device__ __forceinline__ float frombf(unsigned short u){ union{unsigned x; float f;} v; v.x = ((unsigned)u)<<16; return v.f; }

static __device__ __forceinline__ void gload16(const void* g, void* l){
  __builtin_amdgcn_global_load_lds((const __attribute__((address_space(1))) void*)g,
                                   (__attribute__((address_space(3))) void*)l, 16, 0, 0);
}

// ---- K0: weights f32 [512][256] -> bf16 transposed, two copies (pre-swizzled + linear)
__global__ void k_wt(const float* __restrict__ w0, const float* __restrict__ w1,
                     const float* __restrict__ w2, const float* __restrict__ w3,
                     char* __restrict__ wtsw, unsigned short* __restrict__ wtlin){
  int g = blockIdx.x*256 + threadIdx.x;   // m(2) kg(6) n(8)
  int m = g >> 14;
  int kg = (g >> 8) & 63;
  int n = g & 255;
  const float* W = (m==0)?w0:(m==1)?w1:(m==2)?w2:w3;
  unsigned short v[8];
  #pragma unroll
  for (int i=0;i<8;i++) v[i] = f2b(W[(kg*8+i)*DD + n]);
  uint4 u;
  u.x = (unsigned)v[0] | ((unsigned)v[1]<<16);
  u.y = (unsigned)v[2] | ((unsigned)v[3]<<16);
  u.z = (unsigned)v[4] | ((unsigned)v[5]<<16);
  u.w = (unsigned)v[6] | ((unsigned)v[7]<<16);
  *(uint4*)(wtlin + (size_t)m*131072 + n*512 + kg*8) = u;
  int rot = ((kg & 3) + (n >> 1)) & 3;
  *(uint4*)(wtsw + (size_t)m*262144 + n*1024 + (kg>>2)*64 + rot*16) = u;
}

// ---- K1: last-write-wins winner per slot
__global__ void k_winner(const int* __restrict__ ei, const int* __restrict__ ti,
                         int* __restrict__ winner){
  int i = blockIdx.x*256 + threadIdx.x;
  atomicMax(&winner[ei[i]*MT + ti[i]], i);
}

// ---- K_syms: SymGC[s] = sym[s] @ [Wg1_bot | Wc1_bot], stored interleaved:
// short index = s*512 + (c>>5)*64 + (c&15)*4 + ((c>>4)&1)*2 + mat   (c = output col 0..255)
__global__ __launch_bounds__(512, 4)
void k_syms(const float* __restrict__ sym, const char* __restrict__ wtsw,
            unsigned short* __restrict__ symgc){
  __shared__ char Abuf[32768];
  __shared__ char Bbuf[32768];

  int tid = threadIdx.x, lane = tid & 63, wv = tid >> 6;
  int l15 = lane & 15, lg = lane >> 4;
  int wq = wv & 3; bool isC = wv >= 4;
  int s0 = blockIdx.x * 64;

  { // stage A [64 rows][256 k] bf16, chunk-addr ^ ((row&15)<<4)
    int r = tid >> 3;
    int row = s0 + r;
    char* arow = Abuf + r*512;
    unsigned swz = (unsigned)((r & 15) << 4);
    if (row < NSYM){
      const float* src = sym + (size_t)row*DD;
      #pragma unroll
      for (int i=0;i<4;i++){
        int c = (tid & 7) + i*8;
        float4 x = *(const float4*)(src + c*8);
        float4 y = *(const float4*)(src + c*8 + 4);
        uint4 u; u.x=pk2(x.x,x.y); u.y=pk2(x.z,x.w); u.z=pk2(y.x,y.y); u.w=pk2(y.z,y.w);
        *(uint4*)(arow + ((c*16) ^ swz)) = u;
      }
    } else {
      uint4 u = {0,0,0,0};
      #pragma unroll
      for (int i=0;i<4;i++){
        int c = (tid & 7) + i*8;
        *(uint4*)(arow + ((c*16) ^ swz)) = u;
      }
    }
  }
  __syncthreads();

  f32x4 acc[4][4];
  f32x4 zz = {0.f,0.f,0.f,0.f};
  #pragma unroll
  for (int rt=0;rt<4;rt++)
    #pragma unroll
    for (int ct=0;ct<4;ct++) acc[rt][ct]=zz;

  const char* wbG = wtsw;              // Wg1
  const char* wbC = wtsw + 262144;     // Wc1

  for (int kt=0; kt<8; ++kt){
    __syncthreads();
    #pragma unroll
    for (int i=0;i<4;i++){
      int n = wv*64 + i*16 + (lane>>2);
      const char* src = ((n < 256)? wbG : wbC) + (size_t)(n & 255)*1024 + (8+kt)*64 + (lane&3)*16;
      gload16(src, Bbuf + n*64 + (lane&3)*16);
    }
    __syncthreads();
    int koff = kt*64 + lg*16;
    bf16x8 a[4], b[4];
    #pragma unroll
    for (int rt=0;rt<4;rt++)
      a[rt] = *(const bf16x8*)(Abuf + (rt*16 + l15)*512 + (koff ^ (l15<<4)));
    #pragma unroll
    for (int ct=0;ct<4;ct++){
      int nn = (isC?256:0) + wq*64 + ct*16 + l15;
      b[ct] = *(const bf16x8*)(Bbuf + nn*64 + (((lg + (nn>>1)) & 3)<<4));
    }
    #pragma unroll
    for (int rt=0;rt<4;rt++)
      #pragma unroll
      for (int ct=0;ct<4;ct++)
        acc[rt][ct] = __builtin_amdgcn_mfma_f32_16x16x32_bf16(a[rt], b[ct], acc[rt][ct], 0,0,0);
  }

  #pragma unroll
  for (int rt=0;rt<4;rt++)
    #pragma unroll
    for (int ct=0;ct<4;ct++)
      #pragma unroll
      for (int j=0;j<4;j++){
        int row = s0 + rt*16 + lg*4 + j;
        int idx = (wq*2 + (ct>>1))*64 + l15*4 + (ct&1)*2 + (isC?1:0);
        symgc[(size_t)row*512 + idx] = f2b(acc[rt][ct][j]);
      }
}

// ---- K2: gate1. 64 slots (2 expr)/block, 8 waves; wave wv owns ALL 64 rows x 32 cols
// (wv*32..+31) x BOTH matrices. Pipelined B staging: stage BC[kt] during G-phase,
// BG[kt+1] during C-phase. Epilogue entirely in-register.
__global__ __launch_bounds__(512, 2)
void k_gate1(const float* __restrict__ expr, const char* __restrict__ wtsw,
             const float* __restrict__ bg, const float* __restrict__ bc,
             const int* __restrict__ winner, const int* __restrict__ appsym,
             const unsigned short* __restrict__ symgc,
             float* __restrict__ outcomb){
  __shared__ char A[32768];
  __shared__ char BGb[16384];
  __shared__ char BCb[16384];

  int tid = threadIdx.x, lane = tid & 63, wv = tid >> 6;
  int l15 = lane & 15, lg = lane >> 4;
  int s0 = blockIdx.x * 64;

  int wn = winner[s0 + lane];
  int sidv = (wn >= 0) ? appsym[wn] : 0;
  unsigned long long hwmask = __ballot(wn >= 0);

  const char* wsG = wtsw;            // Wg1 (top half rows via kt 0..7)
  const char* wsC = wtsw + 262144;   // Wc1

  { // stage A = orig expr [64][256] bf16, chunk ^ ((row&15)<<4)
    int r = tid >> 3;
    const float* src = expr + (size_t)(s0 + r)*DD;
    char* arow = A + r*512;
    unsigned swz = (unsigned)((r & 15) << 4);
    #pragma unroll
    for (int i=0;i<4;i++){
      int c = (tid & 7) + i*8;
      float4 x = *(const float4*)(src + c*8);
      float4 y = *(const float4*)(src + c*8 + 4);
      uint4 u; u.x=pk2(x.x,x.y); u.y=pk2(x.z,x.w); u.z=pk2(y.x,y.y); u.w=pk2(y.z,y.w);
      *(uint4*)(arow + ((c*16) ^ swz)) = u;
    }
  }
  { // prologue: stage BG[0], BC[0] (linear dest; rotation pre-baked in ws)
    #pragma unroll
    for (int i=0;i<2;i++){
      int g = tid + i*512;
      int n = g >> 2, p = g & 3;
      gload16(wsG + (size_t)n*1024 + p*16, BGb + g*16);
      gload16(wsC + (size_t)n*1024 + p*16, BCb + g*16);
    }
  }
  __syncthreads();

  f32x4 accG[4][2], accC[4][2];
  f32x4 zz = {0.f,0.f,0.f,0.f};
  #pragma unroll
  for (int rt=0;rt<4;rt++){ accG[rt][0]=zz; accG[rt][1]=zz; accC[rt][0]=zz; accC[rt][1]=zz; }

  int nl0 = wv*32 + l15;           // ct=0 column
  int rot0 = ((lg + (nl0>>1)) & 3) << 4;
  int rot1 = ((lg + ((nl0+16)>>1)) & 3) << 4;
  int boff0 = nl0*64 + rot0;
  int boff1 = (nl0+16)*64 + rot1;

  for (int kt=0; kt<8; ++kt){
    // ---- G-phase: stage BC[kt] (kt>0), compute G MFMAs, keep A-frags
    if (kt > 0){
      #pragma unroll
      for (int i=0;i<2;i++){
        int g = tid + i*512;
        int n = g >> 2, p = g & 3;
        gload16(wsC + (size_t)n*1024 + kt*64 + p*16, BCb + g*16);
      }
    }
    int koff = kt*64 + lg*16;
    bf16x8 a[4];
    #pragma unroll
    for (int rt=0;rt<4;rt++)
      a[rt] = *(const bf16x8*)(A + (rt*16 + l15)*512 + (koff ^ (l15<<4)));
    {
      bf16x8 b0 = *(const bf16x8*)(BGb + boff0);
      bf16x8 b1 = *(const bf16x8*)(BGb + boff1);
      #pragma unroll
      for (int rt=0;rt<4;rt++){
        accG[rt][0] = __builtin_amdgcn_mfma_f32_16x16x32_bf16(a[rt], b0, accG[rt][0], 0,0,0);
        accG[rt][1] = __builtin_amdgcn_mfma_f32_16x16x32_bf16(a[rt], b1, accG[rt][1], 0,0,0);
      }
    }
    __syncthreads();
    // ---- C-phase: stage BG[kt+1] (kt<7), compute C MFMAs (reuse a[])
    if (kt < 7){
      #pragma unroll
      for (int i=0;i<2;i++){
        int g = tid + i*512;
        int n = g >> 2, p = g & 3;
        gload16(wsG + (size_t)n*1024 + (kt+1)*64 + p*16, BGb + g*16);
      }
    }
    {
      bf16x8 b0 = *(const bf16x8*)(BCb + boff0);
      bf16x8 b1 = *(const bf16x8*)(BCb + boff1);
      #pragma unroll
      for (int rt=0;rt<4;rt++){
        accC[rt][0] = __builtin_amdgcn_mfma_f32_16x16x32_bf16(a[rt], b0, accC[rt][0], 0,0,0);
        accC[rt][1] = __builtin_amdgcn_mfma_f32_16x16x32_bf16(a[rt], b1, accC[rt][1], 0,0,0);
      }
    }
    __syncthreads();
  }

  // ---- epilogue: fully in-register combine + token-mean
  float bgv[2], bcv[2];
  #pragma unroll
  for (int ct=0;ct<2;ct++){ int c = wv*32+ct*16+l15; bgv[ct]=bg[c]; bcv[ct]=bc[c]; }

  float osum[2][2] = {{0.f,0.f},{0.f,0.f}};   // [expr-half][ct]
  #pragma unroll
  for (int rt=0;rt<4;rt++){
    #pragma unroll
    for (int j=0;j<4;j++){
      int row = rt*16 + lg*4 + j;
      int sid = __shfl(sidv, row);
      const ushort4 sv = *(const ushort4*)(symgc + (size_t)sid*512 + wv*64 + l15*4);
      bool hw = (hwmask >> row) & 1ull;
      const float* prow = expr + (size_t)(s0+row)*DD;
      #pragma unroll
      for (int ct=0;ct<2;ct++){
        float p = prow[wv*32 + ct*16 + l15];
        float gl = accG[rt][ct][j] + frombf(sv[ct*2+0]) + bgv[ct];
        float cl = accC[rt][ct][j] + frombf(sv[ct*2+1]) + bcv[ct];
        float f = 1.f/(1.f + __expf(-gl));
        float cd = fmaxf(cl, 0.f);
        float o = hw ? (f*p + (1.f-f)*cd) : p;
        osum[rt>>1][ct] += o;
      }
    }
  }
  #pragma unroll
  for (int e=0;e<2;e++)
    #pragma unroll
    for (int ct=0;ct<2;ct++){
      float s = osum[e][ct];
      s += __shfl_xor(s, 16);
      s += __shfl_xor(s, 32);
      if (lane < 16)
        outcomb[(size_t)(blockIdx.x*2 + e)*DD + wv*32 + ct*16 + l15] = s * (1.f/32.f);
    }
}

// ---- K3: gate2 over 64 expressions per block, in-place on d_out (validated; uses wt_lin)
__global__ __launch_bounds__(1024)
void k_gate2(const float* __restrict__ prevn, const float* comb,
             const float* __restrict__ bg, const float* __restrict__ bc,
             const unsigned short* __restrict__ Wgt, const unsigned short* __restrict__ Wct,
             float* out){
  __shared__ char A[64*1024];

  int tid  = threadIdx.x;
  int lane = tid & 63;
  int wv   = tid >> 6;
  int wr = wv >> 3, wc = wv & 7;
  int l15 = lane & 15, lg = lane >> 4;
  int e0 = blockIdx.x * 64;

  { // stage A = [prev | combined]
    int row = tid >> 4, cb = (tid & 15)*16;
    unsigned swz = (unsigned)((row&7)<<4);
    const float* src = prevn + (size_t)(e0+row)*DD + cb;
    const float* s2  = comb  + (size_t)(e0+row)*DD + cb;
    char* arow = A + row*1024;
    #pragma unroll
    for (int i=0;i<2;i++){
      float4 x = *(const float4*)(src + i*8);
      float4 y = *(const float4*)(src + i*8 + 4);
      uint4 u; u.x=pk2(x.x,x.y); u.y=pk2(x.z,x.w); u.z=pk2(y.x,y.y); u.w=pk2(y.z,y.w);
      *(uint4*)(arow + (((cb+i*8)*2) ^ swz)) = u;
    }
    #pragma unroll
    for (int i=0;i<2;i++){
      float4 x = *(const float4*)(s2 + i*8);
      float4 y = *(const float4*)(s2 + i*8 + 4);
      uint4 u; u.x=pk2(x.x,x.y); u.y=pk2(x.z,x.w); u.z=pk2(y.x,y.y); u.w=pk2(y.z,y.w);
      *(uint4*)(arow + (((256+cb+i*8)*2) ^ swz)) = u;
    }
  }
  __syncthreads();

  unsigned swzL = (unsigned)((l15&7)<<4);
  const char* pa0 = A + (wr*32 + l15)*1024;
  const char* pa1 = pa0 + 16*1024;
  const unsigned short* wg0 = Wgt + (size_t)(wc*32 + l15)*512 + lg*8;
  const unsigned short* wc0 = Wct + (size_t)(wc*32 + l15)*512 + lg*8;

  f32x4 accg[2][2], accc[2][2];
  f32x4 zz = {0.f,0.f,0.f,0.f};
  #pragma unroll
  for (int ri=0;ri<2;ri++){ accg[ri][0]=zz; accg[ri][1]=zz; accc[ri][0]=zz; accc[ri][1]=zz; }

  for (int ks=0; ks<16; ++ks){
    int koff = (ks*64 + lg*16) ^ (int)swzL;
    bf16x8 a0 = *(const bf16x8*)(pa0 + koff);
    bf16x8 a1 = *(const bf16x8*)(pa1 + koff);
    int kw = ks*32;
    #pragma unroll
    for (int ct=0; ct<2; ++ct){
      bf16x8 b = *(const bf16x8*)(wg0 + ct*16*512 + kw);
      accg[0][ct] = __builtin_amdgcn_mfma_f32_16x16x32_bf16(a0, b, accg[0][ct], 0,0,0);
      accg[1][ct] = __builtin_amdgcn_mfma_f32_16x16x32_bf16(a1, b, accg[1][ct], 0,0,0);
    }
  }

  float bgv[2], bcv[2];
  #pragma unroll
  for (int ct=0;ct<2;ct++){ int c = wc*32+ct*16+l15; bgv[ct]=bg[c]; bcv[ct]=bc[c]; }
  #pragma unroll
  for (int ri=0;ri<2;ri++)
    #pragma unroll
    for (int ct=0;ct<2;ct++)
      #pragma unroll
      for (int j=0;j<4;j++)
        accg[ri][ct][j] = 1.f/(1.f + __expf(-(accg[ri][ct][j] + bgv[ct])));

  for (int ks=0; ks<16; ++ks){
    int koff = (ks*64 + lg*16) ^ (int)swzL;
    bf16x8 a0 = *(const bf16x8*)(pa0 + koff);
    bf16x8 a1 = *(const bf16x8*)(pa1 + koff);
    int kw = ks*32;
    #pragma unroll
    for (int ct=0; ct<2; ++ct){
      bf16x8 b = *(const bf16x8*)(wc0 + ct*16*512 + kw);
      accc[0][ct] = __builtin_amdgcn_mfma_f32_16x16x32_bf16(a0, b, accc[0][ct], 0,0,0);
      accc[1][ct] = __builtin_amdgcn_mfma_f32_16x16x32_bf16(a1, b, accc[1][ct], 0,0,0);
    }
  }

  #pragma unroll
  for (int ct=0; ct<2; ++ct){
    #pragma unroll
    for (int ri=0; ri<2; ++ri){
      #pragma unroll
      for (int j=0;j<4;j++){
        int row = wr*32 + ri*16 + lg*4 + j;
        int col = wc*32 + ct*16 + l15;
        int e = e0 + row;
        float prevv = prevn[(size_t)e*DD + col];
        float fr = accg[ri][ct][j];
        float cand = fmaxf(accc[ri][ct][j] + bcv[ct], 0.f);
        out[(size_t)e*DD + col] = fr*prevv + (1.f-fr)*cand;
      }
    }
  }
}

extern "C" void kernel_launch(void* const* d_in, const int* in_sizes, int n_in,
                              void* d_out, int out_size, void* d_ws, size_t ws_size,
                              hipStream_t stream){
  const float* expr = (const float*)d_in[0];
  const float* sym  = (const float*)d_in[1];
  const float* prevn= (const float*)d_in[2];
  const float* Wg1 = (const float*)d_in[3];
  const float* bg1 = (const float*)d_in[4];
  const float* Wc1 = (const float*)d_in[5];
  const float* bc1 = (const float*)d_in[6];
  const float* Wg2 = (const float*)d_in[7];
  const float* bg2 = (const float*)d_in[8];
  const float* Wc2 = (const float*)d_in[9];
  const float* bc2 = (const float*)d_in[10];
  const int* aei = (const int*)d_in[11];
  const int* ati = (const int*)d_in[12];
  const int* asi = (const int*)d_in[13];
  float* outp = (float*)d_out;

  char* wsb = (char*)d_ws;
  int* winner = (int*)(wsb + WS_WINNER);
  char* wtsw = wsb + WS_WTSW;
  unsigned short* wtlin = (unsigned short*)(wsb + WS_WTLIN);
  unsigned short* symgc = (unsigned short*)(wsb + WS_SYMGC);

  hipMemsetAsync(winner, 0xFF, NSLOT*sizeof(int), stream);
  k_wt<<<256, 256, 0, stream>>>(Wg1, Wc1, Wg2, Wc2, wtsw, wtlin);
  k_winner<<<NAPP/256, 256, 0, stream>>>(aei, ati, winner);
  k_syms<<<NSYMP/64, 512, 0, stream>>>(sym, wtsw, symgc);
  k_gate1<<<NSLOT/64, 512, 0, stream>>>(expr, wtsw, bg1, bc1, winner, asi, symgc, outp);
  k_gate2<<<NE/64, 1024, 0, stream>>>(prevn, outp, bg2, bc2,
                                      wtlin + 262144, wtlin + 393216, outp);
}